// Round 9
// baseline (305.688 us; speedup 1.0000x reference)
//
#include <hip/hip_runtime.h>
#include <math.h>

// Problem constants
static constexpr int Ee  = 1024;
static constexpr int Ss  = 2048;
static constexpr int Bb  = 2;
static constexpr int Hh  = 16;
static constexpr int DHd = 64;
static constexpr int Mm  = Bb * Ss; // 4096
static constexpr int Kk  = 1024;

typedef __attribute__((ext_vector_type(8))) short short8;
typedef __attribute__((ext_vector_type(4))) float f32x4;

// ---------------------------------------------------------------------------
// Packed-swizzled operand layout ("Pk"): Pk[row][kb][gp], row-stride 2048
// shorts (4 KB); kb 0..31; 8 granules of 8 shorts. gl 0..3 = bf16-hi of
// k = kb*32+gl*8..+7, gl|4 = bf16-lo. Stored at gp = gl ^ (row&7).
// ---------------------------------------------------------------------------

__device__ __forceinline__ unsigned short f2bf(float f) {
    unsigned u = __float_as_uint(f);
    u += 0x7fffu + ((u >> 16) & 1u);   // round-to-nearest-even
    return (unsigned short)(u >> 16);
}
__device__ __forceinline__ float bf2f(unsigned short h) {
    return __uint_as_float(((unsigned)h) << 16);
}
__device__ __forceinline__ void hilo(float f, unsigned short& h, unsigned short& l) {
    h = f2bf(f);
    l = f2bf(f - bf2f(h));
}

// ---------------------------------------------------------------------------
__global__ __launch_bounds__(256) void cvt_x_packed(
    const float* __restrict__ in, unsigned short* __restrict__ outp)
{
    const int i   = blockIdx.x * 256 + threadIdx.x;
    const int row = i >> 7;
    const int ki  = i & 127;
    const int kb  = ki >> 2;
    const int gl  = ki & 3;
    const float4 v0 = *(const float4*)&in[(size_t)row * 1024 + ki * 8];
    const float4 v1 = *(const float4*)&in[(size_t)row * 1024 + ki * 8 + 4];
    const float f[8] = {v0.x, v0.y, v0.z, v0.w, v1.x, v1.y, v1.z, v1.w};
    short8 hv, lv;
    #pragma unroll
    for (int j = 0; j < 8; ++j) {
        unsigned short h, l;
        hilo(f[j], h, l);
        hv[j] = (short)h;
        lv[j] = (short)l;
    }
    unsigned short* base = outp + (size_t)row * 2048 + kb * 64;
    const int sw = row & 7;
    *(short8*)(base + ((gl ^ sw) << 3))       = hv;
    *(short8*)(base + (((gl | 4) ^ sw) << 3)) = lv;
}

// ---------------------------------------------------------------------------
__global__ __launch_bounds__(256) void cvt_w_packed(
    const float* __restrict__ W, unsigned short* __restrict__ Wp, int N)
{
    __shared__ float tile[32][65];
    const int kb = blockIdx.x;
    const int n0 = blockIdx.y * 64;
    const int k0 = kb * 32;
    const int t  = threadIdx.x;
    {
        const int kr = t >> 4, nc = t & 15;
        #pragma unroll
        for (int i = 0; i < 2; ++i) {
            const int k = kr + i * 16;
            float4 v = *(const float4*)&W[(size_t)(k0 + k) * N + n0 + nc * 4];
            tile[k][nc * 4 + 0] = v.x;
            tile[k][nc * 4 + 1] = v.y;
            tile[k][nc * 4 + 2] = v.z;
            tile[k][nc * 4 + 3] = v.w;
        }
    }
    __syncthreads();
    const int n  = t >> 2;
    const int gl = t & 3;
    const int ng = n0 + n;
    short8 hv, lv;
    #pragma unroll
    for (int j = 0; j < 8; ++j) {
        unsigned short h, l;
        hilo(tile[gl * 8 + j][n], h, l);
        hv[j] = (short)h;
        lv[j] = (short)l;
    }
    unsigned short* base = Wp + (size_t)ng * 2048 + kb * 64;
    const int sw = ng & 7;
    *(short8*)(base + ((gl ^ sw) << 3))       = hv;
    *(short8*)(base + (((gl | 4) ^ sw) << 3)) = lv;
}

// ---------------------------------------------------------------------------
// QKV GEMM, 8-wave 256x256 double-buffered structure (T3-lite + T5):
// issue next-K-step staging BEFORE computing current step; one barrier per
// K-step; setprio around MFMA clusters. bf16x3, packed-swizzled operands.
// Epilogue -> Q (scaled, plain) + K/V flash swizzled images (as round 7).
// ---------------------------------------------------------------------------
__global__ __launch_bounds__(512, 2) void gemm_qkv_8w(
    const unsigned short* __restrict__ Ap, const unsigned short* __restrict__ Bp,
    const float* __restrict__ bias,
    unsigned short* __restrict__ Qh, unsigned short* __restrict__ Ql,
    unsigned short* __restrict__ Kh, unsigned short* __restrict__ Kl,
    unsigned short* __restrict__ Vh, unsigned short* __restrict__ Vl)
{
    __shared__ __align__(16) unsigned short As[2][256 * 64];  // 64 KB
    __shared__ __align__(16) unsigned short Bs[2][256 * 64];  // 64 KB

    const int t    = threadIdx.x;
    const int m0   = blockIdx.y * 256, n0 = blockIdx.x * 256;
    const int w    = t >> 6, lane = t & 63;
    const int wr   = w >> 2, wc = w & 3;     // wave grid 2M x 4N, tile 128x64
    const int lr   = lane & 15, lk = lane >> 4;
    const int sw   = lr & 7;                 // row&7 == lr&7 for frag rows
    const int wb16 = (t & ~63) * 8;          // wave-uniform LDS base (shorts)

    f32x4 acc[8][4] = {};

#define STAGE(KB, BUF)                                                         \
    {                                                                          \
        const int kb_ = (KB);                                                  \
        _Pragma("unroll")                                                      \
        for (int i = 0; i < 4; ++i) {                                          \
            const int seg = i * 512 + t;                                       \
            const int row = seg >> 3, gp = seg & 7;                            \
            const int lo = i * 512 * 8 + wb16;                                 \
            __builtin_amdgcn_global_load_lds(                                  \
                (const __attribute__((address_space(1))) void*)                \
                    (Ap + (size_t)(m0 + row) * 2048 + kb_ * 64 + gp * 8),      \
                (__attribute__((address_space(3))) void*)(&As[BUF][lo]),       \
                16, 0, 0);                                                     \
            __builtin_amdgcn_global_load_lds(                                  \
                (const __attribute__((address_space(1))) void*)                \
                    (Bp + (size_t)(n0 + row) * 2048 + kb_ * 64 + gp * 8),      \
                (__attribute__((address_space(3))) void*)(&Bs[BUF][lo]),       \
                16, 0, 0);                                                     \
        }                                                                      \
    }

    STAGE(0, 0);
    __syncthreads();   // drains vmcnt -> buf0 ready

    #pragma unroll 1
    for (int kb = 0; kb < 32; ++kb) {
        const int cur = kb & 1;
        // issue next tile's loads FIRST (hidden under this step's compute)
        if (kb < 31) STAGE(kb + 1, cur ^ 1);
        __builtin_amdgcn_sched_barrier(0);   // pin issue-before-compute

        // B fragments for this kb (kept resident across both halves)
        short8 bvh[4], bvl[4];
        #pragma unroll
        for (int n = 0; n < 4; ++n) {
            const int rb = (wc * 64 + n * 16 + lr) * 64;
            bvh[n] = *(const short8*)&Bs[cur][rb + ((lk ^ sw) << 3)];
            bvl[n] = *(const short8*)&Bs[cur][rb + (((lk | 4) ^ sw) << 3)];
        }
        #pragma unroll
        for (int half = 0; half < 2; ++half) {
            short8 avh[4], avl[4];
            #pragma unroll
            for (int m = 0; m < 4; ++m) {
                const int rb = (wr * 128 + (half * 4 + m) * 16 + lr) * 64;
                avh[m] = *(const short8*)&As[cur][rb + ((lk ^ sw) << 3)];
                avl[m] = *(const short8*)&As[cur][rb + (((lk | 4) ^ sw) << 3)];
            }
            __builtin_amdgcn_s_setprio(1);
            #pragma unroll
            for (int m = 0; m < 4; ++m)
                #pragma unroll
                for (int n = 0; n < 4; ++n) {
                    f32x4 a = acc[half * 4 + m][n];
                    a = __builtin_amdgcn_mfma_f32_16x16x32_bf16(avh[m], bvh[n], a, 0, 0, 0);
                    a = __builtin_amdgcn_mfma_f32_16x16x32_bf16(avh[m], bvl[n], a, 0, 0, 0);
                    a = __builtin_amdgcn_mfma_f32_16x16x32_bf16(avl[m], bvh[n], a, 0, 0, 0);
                    acc[half * 4 + m][n] = a;
                }
            __builtin_amdgcn_s_setprio(0);
        }
        __syncthreads();   // drains prefetch (had full compute window) + sync
    }
#undef STAGE

    // Epilogue. C/D frag: col = lane&15, row = lk*4 + r.
    #pragma unroll
    for (int n = 0; n < 4; ++n) {
        const int gcol = n0 + wc * 64 + n * 16 + lr;
        const float bb = bias[gcol];
        const int c  = gcol >> 10;          // block-uniform (256 | 1024)
        const int hd = (gcol >> 6) & 15;
        const int d  = gcol & 63;
        #pragma unroll
        for (int m = 0; m < 8; ++m) {
            #pragma unroll
            for (int r = 0; r < 4; ++r) {
                const int grow = m0 + wr * 128 + m * 16 + lk * 4 + r;
                const int b = grow >> 11, s = grow & (Ss - 1);
                const int bh = b * Hh + hd;
                const int kv = s & 63;
                float v = acc[m][n][r] + bb;
                if (c == 0) v *= 0.125f;    // fold 1/sqrt(64) into Q
                unsigned short vh_, vl_;
                hilo(v, vh_, vl_);
                size_t off;
                unsigned short *ph, *pl;
                if (c == 0) {
                    off = ((size_t)bh * Ss + s) * 64 + d;
                    ph = Qh; pl = Ql;
                } else if (c == 1) {
                    off = (size_t)bh * 131072 + (size_t)(s >> 6) * 4096 +
                          kv * 64 + (d ^ ((kv & 7) << 3));
                    ph = Kh; pl = Kl;
                } else {
                    off = (size_t)bh * 131072 + (size_t)(s >> 6) * 4096 +
                          d * 64 + (kv ^ ((d & 7) << 3));
                    ph = Vh; pl = Vl;
                }
                ph[off] = vh_;
                pl[off] = vl_;
            }
        }
    }
}

// ---------------------------------------------------------------------------
// Out-projection GEMM: proven round-7 128x128 / 4-wave structure, fp32 out.
// ---------------------------------------------------------------------------
__global__ __launch_bounds__(256) void gemm_out(
    const unsigned short* __restrict__ Ap, const unsigned short* __restrict__ Bp,
    const float* __restrict__ bias, float* __restrict__ O0)
{
    constexpr int N = 1024;
    __shared__ __align__(16) unsigned short As[128 * 64];
    __shared__ __align__(16) unsigned short Bs[128 * 64];

    const int t  = threadIdx.x;
    const int m0 = blockIdx.y * 128, n0 = blockIdx.x * 128;
    const int w  = t >> 6, lane = t & 63;
    const int wr = w >> 1, wc = w & 1;
    const int lr = lane & 15, lk = lane >> 4;
    const int sw = lr & 7;

    f32x4 acc[4][4] = {};

    #pragma unroll 1
    for (int kb = 0; kb < 32; ++kb) {
        #pragma unroll
        for (int i = 0; i < 4; ++i) {
            const int seg = t + i * 256;
            const int row = seg >> 3, gp = seg & 7;
            const size_t goA = (size_t)(m0 + row) * 2048 + kb * 64 + gp * 8;
            const size_t goB = (size_t)(n0 + row) * 2048 + kb * 64 + gp * 8;
            const int lo = (i * 256 + (t & ~63)) * 8;
            __builtin_amdgcn_global_load_lds(
                (const __attribute__((address_space(1))) void*)(Ap + goA),
                (__attribute__((address_space(3))) void*)(As + lo), 16, 0, 0);
            __builtin_amdgcn_global_load_lds(
                (const __attribute__((address_space(1))) void*)(Bp + goB),
                (__attribute__((address_space(3))) void*)(Bs + lo), 16, 0, 0);
        }
        __syncthreads();

        short8 avh[4], avl[4], bvh[4], bvl[4];
        #pragma unroll
        for (int m = 0; m < 4; ++m) {
            const int rb = (wr * 64 + m * 16 + lr) * 64;
            avh[m] = *(const short8*)&As[rb + ((lk ^ sw) << 3)];
            avl[m] = *(const short8*)&As[rb + (((lk | 4) ^ sw) << 3)];
        }
        #pragma unroll
        for (int n = 0; n < 4; ++n) {
            const int rb = (wc * 64 + n * 16 + lr) * 64;
            bvh[n] = *(const short8*)&Bs[rb + ((lk ^ sw) << 3)];
            bvl[n] = *(const short8*)&Bs[rb + (((lk | 4) ^ sw) << 3)];
        }
        #pragma unroll
        for (int m = 0; m < 4; ++m)
            #pragma unroll
            for (int n = 0; n < 4; ++n) {
                acc[m][n] = __builtin_amdgcn_mfma_f32_16x16x32_bf16(
                    avh[m], bvh[n], acc[m][n], 0, 0, 0);
                acc[m][n] = __builtin_amdgcn_mfma_f32_16x16x32_bf16(
                    avh[m], bvl[n], acc[m][n], 0, 0, 0);
                acc[m][n] = __builtin_amdgcn_mfma_f32_16x16x32_bf16(
                    avl[m], bvh[n], acc[m][n], 0, 0, 0);
            }
        __syncthreads();
    }

    #pragma unroll
    for (int n = 0; n < 4; ++n) {
        const int gcol = n0 + wc * 64 + n * 16 + lr;
        const float bb = bias[gcol];
        #pragma unroll
        for (int m = 0; m < 4; ++m) {
            #pragma unroll
            for (int r = 0; r < 4; ++r) {
                const int grow = m0 + wr * 64 + m * 16 + lk * 4 + r;
                O0[(size_t)grow * N + gcol] = acc[m][n][r] + bb;
            }
        }
    }
}

// ---------------------------------------------------------------------------
// Flash attention (verified round 6/7): swapped QK^T, fixed-shift softmax,
// bf16x3 GEMMs, epilogue -> AO in packed-swizzled Pk layout.
// ---------------------------------------------------------------------------
__global__ __launch_bounds__(256, 4) void flash_mfma(
    const unsigned short* __restrict__ Qgh, const unsigned short* __restrict__ Qgl,
    const unsigned short* __restrict__ Kgh, const unsigned short* __restrict__ Kgl,
    const unsigned short* __restrict__ Vgh, const unsigned short* __restrict__ Vgl,
    unsigned short* __restrict__ AOp)
{
    __shared__ __align__(16) unsigned short Ksh[4096], Ksl[4096];
    __shared__ __align__(16) unsigned short Vsh[4096], Vsl[4096];
    __shared__ __align__(16) unsigned short Ph[4096], Pl[4096];

    const int t    = threadIdx.x;
    const int w    = t >> 6, lane = t & 63;
    const int lr   = lane & 15, g = lane >> 4;
    const int bid  = blockIdx.x;
    const int qt   = 31 - (bid >> 5);
    const int bh   = bid & 31;
    const int b    = bh >> 4, h = bh & 15;
    const int q0   = qt * 64;
    const int wq0  = w * 16;
    const int qloc = wq0 + lr;
    const int qg   = q0 + qloc;

    short8 qbh[2], qbl[2];
    #pragma unroll
    for (int ks = 0; ks < 2; ++ks) {
        const size_t off = ((size_t)bh * Ss + qg) * 64 + ks * 32 + g * 8;
        qbh[ks] = *(const short8*)&Qgh[off];
        qbl[ks] = *(const short8*)&Qgl[off];
    }

    f32x4 o[4] = {};
    float lp = 0.f;
    const int swq = (lr & 7) << 3;

    const int nkt = qt + 1;
    #pragma unroll 1
    for (int kt = 0; kt < nkt; ++kt) {
        const size_t gb = ((size_t)bh * 32 + kt) * 4096;
        #pragma unroll
        for (int i = 0; i < 2; ++i) {
            const int seg = i * 256 + t;
            const int lo = (i * 256 + (t & ~63)) * 8;
            __builtin_amdgcn_global_load_lds(
                (const __attribute__((address_space(1))) void*)(Kgh + gb + seg * 8),
                (__attribute__((address_space(3))) void*)(Ksh + lo), 16, 0, 0);
            __builtin_amdgcn_global_load_lds(
                (const __attribute__((address_space(1))) void*)(Kgl + gb + seg * 8),
                (__attribute__((address_space(3))) void*)(Ksl + lo), 16, 0, 0);
            __builtin_amdgcn_global_load_lds(
                (const __attribute__((address_space(1))) void*)(Vgh + gb + seg * 8),
                (__attribute__((address_space(3))) void*)(Vsh + lo), 16, 0, 0);
            __builtin_amdgcn_global_load_lds(
                (const __attribute__((address_space(1))) void*)(Vgl + gb + seg * 8),
                (__attribute__((address_space(3))) void*)(Vsl + lo), 16, 0, 0);
        }
        __syncthreads();

        f32x4 s[4] = {};
        #pragma unroll
        for (int ks = 0; ks < 2; ++ks) {
            const int d0 = ks * 32 + g * 8;
            #pragma unroll
            for (int n = 0; n < 4; ++n) {
                const int kv = n * 16 + lr;
                const int idx = kv * 64 + (d0 ^ ((kv & 7) << 3));
                const short8 kh = *(const short8*)&Ksh[idx];
                const short8 kl = *(const short8*)&Ksl[idx];
                s[n] = __builtin_amdgcn_mfma_f32_16x16x32_bf16(kh, qbh[ks], s[n], 0, 0, 0);
                s[n] = __builtin_amdgcn_mfma_f32_16x16x32_bf16(kh, qbl[ks], s[n], 0, 0, 0);
                s[n] = __builtin_amdgcn_mfma_f32_16x16x32_bf16(kl, qbh[ks], s[n], 0, 0, 0);
            }
        }

        if (kt == qt) {
            #pragma unroll
            for (int n = 0; n < 4; ++n)
                #pragma unroll
                for (int r = 0; r < 4; ++r) {
                    const int kv = kt * 64 + n * 16 + g * 4 + r;
                    if (kv > qg) s[n][r] = -INFINITY;
                }
        }

        #pragma unroll
        for (int n = 0; n < 4; ++n) {
            const float p0 = exp2f(fmaf(s[n][0], 1.44269504f, -23.0831184f));
            const float p1 = exp2f(fmaf(s[n][1], 1.44269504f, -23.0831184f));
            const float p2 = exp2f(fmaf(s[n][2], 1.44269504f, -23.0831184f));
            const float p3 = exp2f(fmaf(s[n][3], 1.44269504f, -23.0831184f));
            lp += (p0 + p1) + (p2 + p3);
            const unsigned a0 = __float_as_uint(p0), a1 = __float_as_uint(p1);
            const unsigned a2 = __float_as_uint(p2), a3 = __float_as_uint(p3);
            uint2 uh, ul;
            uh.x = (a0 >> 16) | (a1 & 0xffff0000u);
            uh.y = (a2 >> 16) | (a3 & 0xffff0000u);
            const float r0 = p0 - __uint_as_float(a0 & 0xffff0000u);
            const float r1 = p1 - __uint_as_float(a1 & 0xffff0000u);
            const float r2 = p2 - __uint_as_float(a2 & 0xffff0000u);
            const float r3 = p3 - __uint_as_float(a3 & 0xffff0000u);
            ul.x = (__float_as_uint(r0) >> 16) | (__float_as_uint(r1) & 0xffff0000u);
            ul.y = (__float_as_uint(r2) >> 16) | (__float_as_uint(r3) & 0xffff0000u);
            const int kv0 = n * 16 + g * 4;
            const int idx = qloc * 64 + (kv0 ^ swq);
            *(uint2*)&Ph[idx] = uh;
            *(uint2*)&Pl[idx] = ul;
        }

        #pragma unroll
        for (int ks = 0; ks < 2; ++ks) {
            const int kv0 = ks * 32 + g * 8;
            const int pidx = qloc * 64 + (kv0 ^ swq);
            const short8 pah = *(const short8*)&Ph[pidx];
            const short8 pal = *(const short8*)&Pl[pidx];
            #pragma unroll
            for (int df = 0; df < 4; ++df) {
                const int d = df * 16 + lr;
                const int vidx = d * 64 + (kv0 ^ ((d & 7) << 3));
                const short8 vh_ = *(const short8*)&Vsh[vidx];
                const short8 vl_ = *(const short8*)&Vsl[vidx];
                o[df] = __builtin_amdgcn_mfma_f32_16x16x32_bf16(pah, vh_, o[df], 0, 0, 0);
                o[df] = __builtin_amdgcn_mfma_f32_16x16x32_bf16(pah, vl_, o[df], 0, 0, 0);
                o[df] = __builtin_amdgcn_mfma_f32_16x16x32_bf16(pal, vh_, o[df], 0, 0, 0);
            }
        }
        __syncthreads();
    }

    lp += __shfl_xor(lp, 16);
    lp += __shfl_xor(lp, 32);
    float linv[4];
    #pragma unroll
    for (int r = 0; r < 4; ++r)
        linv[r] = 1.f / __shfl(lp, g * 4 + r);

    #pragma unroll
    for (int df = 0; df < 4; ++df) {
        const int k = h * 64 + df * 16 + lr;
        const int kb2 = k >> 5, gl = (k >> 3) & 3, el = k & 7;
        #pragma unroll
        for (int r = 0; r < 4; ++r) {
            const int q = q0 + wq0 + g * 4 + r;
            const int m = b * Ss + q;
            const float v = o[df][r] * linv[r];
            const unsigned a = __float_as_uint(v);
            const unsigned short hh = (unsigned short)(a >> 16);
            const float rr = v - __uint_as_float(a & 0xffff0000u);
            const unsigned short ll = (unsigned short)(__float_as_uint(rr) >> 16);
            unsigned short* bse = AOp + (size_t)m * 2048 + kb2 * 64;
            const int sw = m & 7;
            bse[((gl ^ sw) << 3) + el]       = hh;
            bse[(((gl | 4) ^ sw) << 3) + el] = ll;
        }
    }
}

// ---------------------------------------------------------------------------
// Workspace (80 MB):
//   0: Qh(8) 8: Ql(8) 16: Kh(8) 24: Kl(8) 32: Vh(8) 40: Vl(8)
//   48: Xp(16) -> reused as AOp(16)
//   64: Wqkvp(12)   76: Woutp(4)
// ---------------------------------------------------------------------------
extern "C" void kernel_launch(void* const* d_in, const int* in_sizes, int n_in,
                              void* d_out, int out_size, void* d_ws, size_t ws_size,
                              hipStream_t stream)
{
    const float* x     = (const float*)d_in[0];
    const float* w_qkv = (const float*)d_in[1];
    const float* b_qkv = (const float*)d_in[2];
    const float* w_out = (const float*)d_in[3];
    const float* b_out = (const float*)d_in[4];
    float* out = (float*)d_out;

    char* wsb = (char*)d_ws;
    const size_t MB = 1024ull * 1024ull;
    unsigned short* Qh  = (unsigned short*)(wsb + 0 * MB);
    unsigned short* Ql  = (unsigned short*)(wsb + 8 * MB);
    unsigned short* Kh  = (unsigned short*)(wsb + 16 * MB);
    unsigned short* Kl  = (unsigned short*)(wsb + 24 * MB);
    unsigned short* Vh  = (unsigned short*)(wsb + 32 * MB);
    unsigned short* Vl  = (unsigned short*)(wsb + 40 * MB);
    unsigned short* Xp  = (unsigned short*)(wsb + 48 * MB);
    unsigned short* AOp = (unsigned short*)(wsb + 48 * MB);  // reuses Xp
    unsigned short* Wqkvp = (unsigned short*)(wsb + 64 * MB);
    unsigned short* Woutp = (unsigned short*)(wsb + 76 * MB);

    cvt_x_packed<<<2048, 256, 0, stream>>>(x, Xp);
    cvt_w_packed<<<dim3(32, 3072 / 64), 256, 0, stream>>>(w_qkv, Wqkvp, 3072);
    cvt_w_packed<<<dim3(32, 1024 / 64), 256, 0, stream>>>(w_out, Woutp, 1024);

    // 1) QKV projection (8-wave 256x256, issue-early dbuf) -> Q + K/V images
    gemm_qkv_8w<<<dim3(3072 / 256, Mm / 256), 512, 0, stream>>>(
        Xp, Wqkvp, b_qkv, Qh, Ql, Kh, Kl, Vh, Vl);

    // 2) Flash attention -> AOp (packed-swizzled)
    flash_mfma<<<dim3(1024), 256, 0, stream>>>(
        Qh, Ql, Kh, Kl, Vh, Vl, AOp);

    // 3) Output projection -> fp32 out
    gemm_out<<<dim3(1024 / 128, Mm / 128), 256, 0, stream>>>(
        AOp, Woutp, b_out, out);
}

// Round 10
// 274.855 us; speedup vs baseline: 1.1122x; 1.1122x over previous
//
#include <hip/hip_runtime.h>
#include <math.h>
#include <stdint.h>

// Problem constants
static constexpr int Ee  = 1024;
static constexpr int Ss  = 2048;
static constexpr int Bb  = 2;
static constexpr int Hh  = 16;
static constexpr int DHd = 64;
static constexpr int Mm  = Bb * Ss; // 4096
static constexpr int Kk  = 1024;

typedef __attribute__((ext_vector_type(8))) short short8;
typedef __attribute__((ext_vector_type(4))) float f32x4;

// ---------------------------------------------------------------------------
// Packed-swizzled operand layout ("Pk"): Pk[row][kb][gp], row-stride 2048
// shorts (4 KB); kb 0..31; 8 granules of 8 shorts. gl 0..3 = bf16-hi of
// k = kb*32+gl*8..+7, gl|4 = bf16-lo. Stored at gp = gl ^ (row&7).
// ---------------------------------------------------------------------------

__device__ __forceinline__ unsigned short f2bf(float f) {
    unsigned u = __float_as_uint(f);
    u += 0x7fffu + ((u >> 16) & 1u);   // round-to-nearest-even
    return (unsigned short)(u >> 16);
}
__device__ __forceinline__ float bf2f(unsigned short h) {
    return __uint_as_float(((unsigned)h) << 16);
}
__device__ __forceinline__ void hilo(float f, unsigned short& h, unsigned short& l) {
    h = f2bf(f);
    l = f2bf(f - bf2f(h));
}

// ---------------------------------------------------------------------------
__global__ __launch_bounds__(256) void cvt_x_packed(
    const float* __restrict__ in, unsigned short* __restrict__ outp)
{
    const int i   = blockIdx.x * 256 + threadIdx.x;
    const int row = i >> 7;
    const int ki  = i & 127;
    const int kb  = ki >> 2;
    const int gl  = ki & 3;
    const float4 v0 = *(const float4*)&in[(size_t)row * 1024 + ki * 8];
    const float4 v1 = *(const float4*)&in[(size_t)row * 1024 + ki * 8 + 4];
    const float f[8] = {v0.x, v0.y, v0.z, v0.w, v1.x, v1.y, v1.z, v1.w};
    short8 hv, lv;
    #pragma unroll
    for (int j = 0; j < 8; ++j) {
        unsigned short h, l;
        hilo(f[j], h, l);
        hv[j] = (short)h;
        lv[j] = (short)l;
    }
    unsigned short* base = outp + (size_t)row * 2048 + kb * 64;
    const int sw = row & 7;
    *(short8*)(base + ((gl ^ sw) << 3))       = hv;
    *(short8*)(base + (((gl | 4) ^ sw) << 3)) = lv;
}

// ---------------------------------------------------------------------------
__global__ __launch_bounds__(256) void cvt_w_packed(
    const float* __restrict__ W, unsigned short* __restrict__ Wp, int N)
{
    __shared__ float tile[32][65];
    const int kb = blockIdx.x;
    const int n0 = blockIdx.y * 64;
    const int k0 = kb * 32;
    const int t  = threadIdx.x;
    {
        const int kr = t >> 4, nc = t & 15;
        #pragma unroll
        for (int i = 0; i < 2; ++i) {
            const int k = kr + i * 16;
            float4 v = *(const float4*)&W[(size_t)(k0 + k) * N + n0 + nc * 4];
            tile[k][nc * 4 + 0] = v.x;
            tile[k][nc * 4 + 1] = v.y;
            tile[k][nc * 4 + 2] = v.z;
            tile[k][nc * 4 + 3] = v.w;
        }
    }
    __syncthreads();
    const int n  = t >> 2;
    const int gl = t & 3;
    const int ng = n0 + n;
    short8 hv, lv;
    #pragma unroll
    for (int j = 0; j < 8; ++j) {
        unsigned short h, l;
        hilo(tile[gl * 8 + j][n], h, l);
        hv[j] = (short)h;
        lv[j] = (short)l;
    }
    unsigned short* base = Wp + (size_t)ng * 2048 + kb * 64;
    const int sw = ng & 7;
    *(short8*)(base + ((gl ^ sw) << 3))       = hv;
    *(short8*)(base + (((gl | 4) ^ sw) << 3)) = lv;
}

// ---------------------------------------------------------------------------
// bf16x3 GEMM, counted-vmcnt ring-3 pipeline (T4):
//  - 128x128 tile, 8 waves (2M x 4N -> wave tile 64x32), BK=32.
//  - LDS ring of 3 tile-pairs (96 KB); stage tile kb+2 while computing kb.
//  - asm s_waitcnt vmcnt(4) (only the consumed tile) + raw s_barrier:
//    in-flight loads are NEVER drained in the main loop.
//  - frag loads via inline-asm ds_read_b128 so the compiler's waitcnt
//    legalizer cannot tie them to outstanding global_load_lds (the round-9
//    serializer); manual lgkmcnt(0) + sched_barrier(0) before MFMAs.
// Numerics identical to rounds 7-9 (same MFMA order per accumulator).
// ---------------------------------------------------------------------------
template <int N, bool QKV>
__global__ __launch_bounds__(512, 2) void gemm_ring(
    const unsigned short* __restrict__ Ap, const unsigned short* __restrict__ Bp,
    const float* __restrict__ bias, float* __restrict__ O0,
    unsigned short* __restrict__ Qh, unsigned short* __restrict__ Ql,
    unsigned short* __restrict__ Kh, unsigned short* __restrict__ Kl,
    unsigned short* __restrict__ Vh, unsigned short* __restrict__ Vl)
{
    __shared__ __align__(16) unsigned short As[3][128 * 64];  // 48 KB
    __shared__ __align__(16) unsigned short Bs[3][128 * 64];  // 48 KB

    const int t  = threadIdx.x;
    const int m0 = blockIdx.y * 128, n0 = blockIdx.x * 128;
    const int w  = t >> 6, lane = t & 63;
    const int wr = w >> 2, wc = w & 3;        // wave tile 64(M) x 32(N)
    const int lr = lane & 15, lk = lane >> 4;
    const int sw = lr & 7;

    const unsigned aLds = (unsigned)(uintptr_t)
        (__attribute__((address_space(3))) unsigned short*)&As[0][0];
    const unsigned bLds = (unsigned)(uintptr_t)
        (__attribute__((address_space(3))) unsigned short*)&Bs[0][0];

    f32x4 acc[4][2] = {};

#define STAGE(KB, BUF)                                                        \
    {                                                                         \
        const int kb_ = (KB), buf_ = (BUF);                                   \
        _Pragma("unroll")                                                     \
        for (int i = 0; i < 2; ++i) {                                         \
            const int seg = i * 512 + t;                                      \
            const int row = seg >> 3, gp = seg & 7;                           \
            const int lo = buf_ * 8192 + (i * 512 + (t & ~63)) * 8;           \
            __builtin_amdgcn_global_load_lds(                                 \
                (const __attribute__((address_space(1))) void*)               \
                    (Ap + (size_t)(m0 + row) * 2048 + kb_ * 64 + gp * 8),     \
                (__attribute__((address_space(3))) void*)(&As[0][0] + lo),    \
                16, 0, 0);                                                    \
            __builtin_amdgcn_global_load_lds(                                 \
                (const __attribute__((address_space(1))) void*)               \
                    (Bp + (size_t)(n0 + row) * 2048 + kb_ * 64 + gp * 8),     \
                (__attribute__((address_space(3))) void*)(&Bs[0][0] + lo),    \
                16, 0, 0);                                                    \
        }                                                                     \
    }

    // compute one K-step from ring slot cur (asm frag reads + 24 MFMA)
    auto step = [&](int cur) {
        const unsigned abase = aLds + cur * 16384u;
        const unsigned bbase = bLds + cur * 16384u;
        short8 avh[4], avl[4], bvh[2], bvl[2];
        #pragma unroll
        for (int m = 0; m < 4; ++m) {
            const unsigned rb = abase + (unsigned)((wr * 64 + m * 16 + lr) * 64) * 2u;
            const unsigned ah = rb + (unsigned)(((lk ^ sw) << 3) * 2);
            const unsigned al = rb + (unsigned)((((lk | 4) ^ sw) << 3) * 2);
            asm volatile("ds_read_b128 %0, %1" : "=&v"(avh[m]) : "v"(ah));
            asm volatile("ds_read_b128 %0, %1" : "=&v"(avl[m]) : "v"(al));
        }
        #pragma unroll
        for (int n = 0; n < 2; ++n) {
            const unsigned rb = bbase + (unsigned)((wc * 32 + n * 16 + lr) * 64) * 2u;
            const unsigned bh = rb + (unsigned)(((lk ^ sw) << 3) * 2);
            const unsigned bl = rb + (unsigned)((((lk | 4) ^ sw) << 3) * 2);
            asm volatile("ds_read_b128 %0, %1" : "=&v"(bvh[n]) : "v"(bh));
            asm volatile("ds_read_b128 %0, %1" : "=&v"(bvl[n]) : "v"(bl));
        }
        asm volatile("s_waitcnt lgkmcnt(0)" ::: "memory");
        __builtin_amdgcn_sched_barrier(0);
        __builtin_amdgcn_s_setprio(1);
        #pragma unroll
        for (int m = 0; m < 4; ++m)
            #pragma unroll
            for (int n = 0; n < 2; ++n) {
                f32x4 a = acc[m][n];
                a = __builtin_amdgcn_mfma_f32_16x16x32_bf16(avh[m], bvh[n], a, 0, 0, 0);
                a = __builtin_amdgcn_mfma_f32_16x16x32_bf16(avh[m], bvl[n], a, 0, 0, 0);
                a = __builtin_amdgcn_mfma_f32_16x16x32_bf16(avl[m], bvh[n], a, 0, 0, 0);
                acc[m][n] = a;
            }
        __builtin_amdgcn_s_setprio(0);
    };

    STAGE(0, 0);
    STAGE(1, 1);

    int cur = 0, nxt = 2;
    #pragma unroll 1
    for (int kb = 0; kb < 31; ++kb) {
        asm volatile("s_waitcnt vmcnt(4)" ::: "memory");
        __builtin_amdgcn_s_barrier();
        if (kb <= 29) STAGE(kb + 2, nxt);
        step(cur);
        cur = (cur == 2) ? 0 : cur + 1;
        nxt = (nxt == 2) ? 0 : nxt + 1;
    }
    asm volatile("s_waitcnt vmcnt(0)" ::: "memory");
    __builtin_amdgcn_s_barrier();
    step(cur);   // kb = 31
#undef STAGE

    // Epilogue. C/D frag: col = lane&15, row = lk*4 + r.
    #pragma unroll
    for (int n = 0; n < 2; ++n) {
        const int gcol = n0 + wc * 32 + n * 16 + lr;
        const float bb = bias[gcol];
        if (QKV) {
            const int c  = gcol >> 10;          // block-uniform
            const int hd = (gcol >> 6) & 15;
            const int d  = gcol & 63;
            #pragma unroll
            for (int m = 0; m < 4; ++m) {
                #pragma unroll
                for (int r = 0; r < 4; ++r) {
                    const int grow = m0 + wr * 64 + m * 16 + lk * 4 + r;
                    const int b = grow >> 11, s = grow & (Ss - 1);
                    const int bh = b * Hh + hd;
                    const int kv = s & 63;
                    float v = acc[m][n][r] + bb;
                    if (c == 0) v *= 0.125f;    // fold 1/sqrt(64) into Q
                    unsigned short vh_, vl_;
                    hilo(v, vh_, vl_);
                    size_t off;
                    unsigned short *ph, *pl;
                    if (c == 0) {
                        off = ((size_t)bh * Ss + s) * 64 + d;
                        ph = Qh; pl = Ql;
                    } else if (c == 1) {
                        off = (size_t)bh * 131072 + (size_t)(s >> 6) * 4096 +
                              kv * 64 + (d ^ ((kv & 7) << 3));
                        ph = Kh; pl = Kl;
                    } else {
                        off = (size_t)bh * 131072 + (size_t)(s >> 6) * 4096 +
                              d * 64 + (kv ^ ((d & 7) << 3));
                        ph = Vh; pl = Vl;
                    }
                    ph[off] = vh_;
                    pl[off] = vl_;
                }
            }
        } else {
            #pragma unroll
            for (int m = 0; m < 4; ++m) {
                #pragma unroll
                for (int r = 0; r < 4; ++r) {
                    const int grow = m0 + wr * 64 + m * 16 + lk * 4 + r;
                    O0[(size_t)grow * N + gcol] = acc[m][n][r] + bb;
                }
            }
        }
    }
}

// ---------------------------------------------------------------------------
// Flash attention (verified rounds 6-9): swapped QK^T, fixed-shift softmax,
// bf16x3 GEMMs, epilogue -> AO in packed-swizzled Pk layout.
// ---------------------------------------------------------------------------
__global__ __launch_bounds__(256, 4) void flash_mfma(
    const unsigned short* __restrict__ Qgh, const unsigned short* __restrict__ Qgl,
    const unsigned short* __restrict__ Kgh, const unsigned short* __restrict__ Kgl,
    const unsigned short* __restrict__ Vgh, const unsigned short* __restrict__ Vgl,
    unsigned short* __restrict__ AOp)
{
    __shared__ __align__(16) unsigned short Ksh[4096], Ksl[4096];
    __shared__ __align__(16) unsigned short Vsh[4096], Vsl[4096];
    __shared__ __align__(16) unsigned short Ph[4096], Pl[4096];

    const int t    = threadIdx.x;
    const int w    = t >> 6, lane = t & 63;
    const int lr   = lane & 15, g = lane >> 4;
    const int bid  = blockIdx.x;
    const int qt   = 31 - (bid >> 5);
    const int bh   = bid & 31;
    const int b    = bh >> 4, h = bh & 15;
    const int q0   = qt * 64;
    const int wq0  = w * 16;
    const int qloc = wq0 + lr;
    const int qg   = q0 + qloc;

    short8 qbh[2], qbl[2];
    #pragma unroll
    for (int ks = 0; ks < 2; ++ks) {
        const size_t off = ((size_t)bh * Ss + qg) * 64 + ks * 32 + g * 8;
        qbh[ks] = *(const short8*)&Qgh[off];
        qbl[ks] = *(const short8*)&Qgl[off];
    }

    f32x4 o[4] = {};
    float lp = 0.f;
    const int swq = (lr & 7) << 3;

    const int nkt = qt + 1;
    #pragma unroll 1
    for (int kt = 0; kt < nkt; ++kt) {
        const size_t gb = ((size_t)bh * 32 + kt) * 4096;
        #pragma unroll
        for (int i = 0; i < 2; ++i) {
            const int seg = i * 256 + t;
            const int lo = (i * 256 + (t & ~63)) * 8;
            __builtin_amdgcn_global_load_lds(
                (const __attribute__((address_space(1))) void*)(Kgh + gb + seg * 8),
                (__attribute__((address_space(3))) void*)(Ksh + lo), 16, 0, 0);
            __builtin_amdgcn_global_load_lds(
                (const __attribute__((address_space(1))) void*)(Kgl + gb + seg * 8),
                (__attribute__((address_space(3))) void*)(Ksl + lo), 16, 0, 0);
            __builtin_amdgcn_global_load_lds(
                (const __attribute__((address_space(1))) void*)(Vgh + gb + seg * 8),
                (__attribute__((address_space(3))) void*)(Vsh + lo), 16, 0, 0);
            __builtin_amdgcn_global_load_lds(
                (const __attribute__((address_space(1))) void*)(Vgl + gb + seg * 8),
                (__attribute__((address_space(3))) void*)(Vsl + lo), 16, 0, 0);
        }
        __syncthreads();

        f32x4 s[4] = {};
        #pragma unroll
        for (int ks = 0; ks < 2; ++ks) {
            const int d0 = ks * 32 + g * 8;
            #pragma unroll
            for (int n = 0; n < 4; ++n) {
                const int kv = n * 16 + lr;
                const int idx = kv * 64 + (d0 ^ ((kv & 7) << 3));
                const short8 kh = *(const short8*)&Ksh[idx];
                const short8 kl = *(const short8*)&Ksl[idx];
                s[n] = __builtin_amdgcn_mfma_f32_16x16x32_bf16(kh, qbh[ks], s[n], 0, 0, 0);
                s[n] = __builtin_amdgcn_mfma_f32_16x16x32_bf16(kh, qbl[ks], s[n], 0, 0, 0);
                s[n] = __builtin_amdgcn_mfma_f32_16x16x32_bf16(kl, qbh[ks], s[n], 0, 0, 0);
            }
        }

        if (kt == qt) {
            #pragma unroll
            for (int n = 0; n < 4; ++n)
                #pragma unroll
                for (int r = 0; r < 4; ++r) {
                    const int kv = kt * 64 + n * 16 + g * 4 + r;
                    if (kv > qg) s[n][r] = -INFINITY;
                }
        }

        #pragma unroll
        for (int n = 0; n < 4; ++n) {
            const float p0 = exp2f(fmaf(s[n][0], 1.44269504f, -23.0831184f));
            const float p1 = exp2f(fmaf(s[n][1], 1.44269504f, -23.0831184f));
            const float p2 = exp2f(fmaf(s[n][2], 1.44269504f, -23.0831184f));
            const float p3 = exp2f(fmaf(s[n][3], 1.44269504f, -23.0831184f));
            lp += (p0 + p1) + (p2 + p3);
            const unsigned a0 = __float_as_uint(p0), a1 = __float_as_uint(p1);
            const unsigned a2 = __float_as_uint(p2), a3 = __float_as_uint(p3);
            uint2 uh, ul;
            uh.x = (a0 >> 16) | (a1 & 0xffff0000u);
            uh.y = (a2 >> 16) | (a3 & 0xffff0000u);
            const float r0 = p0 - __uint_as_float(a0 & 0xffff0000u);
            const float r1 = p1 - __uint_as_float(a1 & 0xffff0000u);
            const float r2 = p2 - __uint_as_float(a2 & 0xffff0000u);
            const float r3 = p3 - __uint_as_float(a3 & 0xffff0000u);
            ul.x = (__float_as_uint(r0) >> 16) | (__float_as_uint(r1) & 0xffff0000u);
            ul.y = (__float_as_uint(r2) >> 16) | (__float_as_uint(r3) & 0xffff0000u);
            const int kv0 = n * 16 + g * 4;
            const int idx = qloc * 64 + (kv0 ^ swq);
            *(uint2*)&Ph[idx] = uh;
            *(uint2*)&Pl[idx] = ul;
        }

        #pragma unroll
        for (int ks = 0; ks < 2; ++ks) {
            const int kv0 = ks * 32 + g * 8;
            const int pidx = qloc * 64 + (kv0 ^ swq);
            const short8 pah = *(const short8*)&Ph[pidx];
            const short8 pal = *(const short8*)&Pl[pidx];
            #pragma unroll
            for (int df = 0; df < 4; ++df) {
                const int d = df * 16 + lr;
                const int vidx = d * 64 + (kv0 ^ ((d & 7) << 3));
                const short8 vh_ = *(const short8*)&Vsh[vidx];
                const short8 vl_ = *(const short8*)&Vsl[vidx];
                o[df] = __builtin_amdgcn_mfma_f32_16x16x32_bf16(pah, vh_, o[df], 0, 0, 0);
                o[df] = __builtin_amdgcn_mfma_f32_16x16x32_bf16(pah, vl_, o[df], 0, 0, 0);
                o[df] = __builtin_amdgcn_mfma_f32_16x16x32_bf16(pal, vh_, o[df], 0, 0, 0);
            }
        }
        __syncthreads();
    }

    lp += __shfl_xor(lp, 16);
    lp += __shfl_xor(lp, 32);
    float linv[4];
    #pragma unroll
    for (int r = 0; r < 4; ++r)
        linv[r] = 1.f / __shfl(lp, g * 4 + r);

    #pragma unroll
    for (int df = 0; df < 4; ++df) {
        const int k = h * 64 + df * 16 + lr;
        const int kb2 = k >> 5, gl = (k >> 3) & 3, el = k & 7;
        #pragma unroll
        for (int r = 0; r < 4; ++r) {
            const int q = q0 + wq0 + g * 4 + r;
            const int m = b * Ss + q;
            const float v = o[df][r] * linv[r];
            const unsigned a = __float_as_uint(v);
            const unsigned short hh = (unsigned short)(a >> 16);
            const float rr = v - __uint_as_float(a & 0xffff0000u);
            const unsigned short ll = (unsigned short)(__float_as_uint(rr) >> 16);
            unsigned short* bse = AOp + (size_t)m * 2048 + kb2 * 64;
            const int sw = m & 7;
            bse[((gl ^ sw) << 3) + el]       = hh;
            bse[(((gl | 4) ^ sw) << 3) + el] = ll;
        }
    }
}

// ---------------------------------------------------------------------------
// Workspace (80 MB):
//   0: Qh(8) 8: Ql(8) 16: Kh(8) 24: Kl(8) 32: Vh(8) 40: Vl(8)
//   48: Xp(16) -> reused as AOp(16)
//   64: Wqkvp(12)   76: Woutp(4)
// ---------------------------------------------------------------------------
extern "C" void kernel_launch(void* const* d_in, const int* in_sizes, int n_in,
                              void* d_out, int out_size, void* d_ws, size_t ws_size,
                              hipStream_t stream)
{
    const float* x     = (const float*)d_in[0];
    const float* w_qkv = (const float*)d_in[1];
    const float* b_qkv = (const float*)d_in[2];
    const float* w_out = (const float*)d_in[3];
    const float* b_out = (const float*)d_in[4];
    float* out = (float*)d_out;

    char* wsb = (char*)d_ws;
    const size_t MB = 1024ull * 1024ull;
    unsigned short* Qh  = (unsigned short*)(wsb + 0 * MB);
    unsigned short* Ql  = (unsigned short*)(wsb + 8 * MB);
    unsigned short* Kh  = (unsigned short*)(wsb + 16 * MB);
    unsigned short* Kl  = (unsigned short*)(wsb + 24 * MB);
    unsigned short* Vh  = (unsigned short*)(wsb + 32 * MB);
    unsigned short* Vl  = (unsigned short*)(wsb + 40 * MB);
    unsigned short* Xp  = (unsigned short*)(wsb + 48 * MB);
    unsigned short* AOp = (unsigned short*)(wsb + 48 * MB);  // reuses Xp
    unsigned short* Wqkvp = (unsigned short*)(wsb + 64 * MB);
    unsigned short* Woutp = (unsigned short*)(wsb + 76 * MB);

    cvt_x_packed<<<2048, 256, 0, stream>>>(x, Xp);
    cvt_w_packed<<<dim3(32, 3072 / 64), 256, 0, stream>>>(w_qkv, Wqkvp, 3072);
    cvt_w_packed<<<dim3(32, 1024 / 64), 256, 0, stream>>>(w_out, Woutp, 1024);

    // 1) QKV projection (ring-3 counted-vmcnt) -> Q + K/V flash images
    gemm_ring<3072, true><<<dim3(3072 / 128, Mm / 128), 512, 0, stream>>>(
        Xp, Wqkvp, b_qkv, nullptr, Qh, Ql, Kh, Kl, Vh, Vl);

    // 2) Flash attention -> AOp (packed-swizzled)
    flash_mfma<<<dim3(1024), 256, 0, stream>>>(
        Qh, Ql, Kh, Kl, Vh, Vl, AOp);

    // 3) Output projection (ring-3 counted-vmcnt) -> fp32 out
    gemm_ring<1024, false><<<dim3(1024 / 128, Mm / 128), 512, 0, stream>>>(
        AOp, Woutp, b_out, out,
        nullptr, nullptr, nullptr, nullptr, nullptr, nullptr);
}